// Round 3
// baseline (14839.064 us; speedup 1.0000x reference)
//
#include <hip/hip_runtime.h>
#include <hip/hip_bf16.h>
#include <math.h>

typedef __hip_bfloat16 bf16;

#define D_MODEL 1024
#define NHEAD   16
#define HDK     64
#define BATCH   2
#define SEQ     2048

// ---------------------------------------------------------------------------
// Dtype auto-detect: sample X's first 4096 u16 words. bf16 N(0,1) data has
// exponent field in [96,141] essentially always; float32 data misread as u16
// has random mantissa halves (~59% plausible). flag=1 -> inputs are bf16.
// ---------------------------------------------------------------------------
__global__ void detect_dtype(const unsigned short* __restrict__ x, int* flag) {
    __shared__ int cnt;
    if (threadIdx.x == 0) cnt = 0;
    __syncthreads();
    int local = 0;
    for (int i = threadIdx.x; i < 4096; i += 256) {
        const unsigned short v = x[i];
        const int e = (v >> 7) & 0xFF;
        if (v == 0 || (e >= 96 && e <= 141)) local++;
    }
    atomicAdd(&cnt, local);
    __syncthreads();
    if (threadIdx.x == 0) *flag = (cnt >= 3600) ? 1 : 0;
}

__device__ __forceinline__ float ldIn(const void* p, size_t i, int isbf16) {
    return isbf16 ? __bfloat162float(((const bf16*)p)[i])
                  : ((const float*)p)[i];
}

// ---------------------------------------------------------------------------
// Scalar projection GEMM: C[m][n] = sum_k A[m][k]*W[k][n] + bias[n].
// One block per m-row (4096 blocks, 256 threads); thread covers n, n+256,...
// A-load is block-uniform (scalarizes); W-load is lane-coalesced.
// A_FLAG: A uses detected input dtype (else always bf16 internal buffer).
// OUT_MODE 0: scatter bf16 to (B,H,S,dk).  OUT_MODE 1: row-major, output dtype
// per flag (bf16 or float) -> used for the final O-projection into d_out.
// ---------------------------------------------------------------------------
template<bool A_FLAG, int OUT_MODE>
__global__ void proj_scalar(const void* __restrict__ Araw,
                            const void* __restrict__ Wraw,
                            const void* __restrict__ Braw,
                            void* __restrict__ Cout,
                            const int* __restrict__ flagp) {
    const int flag = *flagp;
    const int m    = blockIdx.x;          // 0..4095
    const int tid  = threadIdx.x;         // 0..255

    float acc[4] = {0.f, 0.f, 0.f, 0.f};
    for (int k = 0; k < D_MODEL; ++k) {
        const float a = A_FLAG
            ? ldIn(Araw, (size_t)m * D_MODEL + k, flag)
            : __bfloat162float(((const bf16*)Araw)[(size_t)m * D_MODEL + k]);
        #pragma unroll
        for (int j = 0; j < 4; ++j) {
            const int n = tid + j * 256;
            acc[j] += a * ldIn(Wraw, (size_t)k * D_MODEL + n, flag);
        }
    }
    #pragma unroll
    for (int j = 0; j < 4; ++j) {
        const int n = tid + j * 256;
        const float v = acc[j] + ldIn(Braw, (size_t)n, flag);
        if (OUT_MODE == 0) {
            const int b = m >> 11, s = m & (SEQ - 1);
            const int h = n >> 6,  d = n & (HDK - 1);
            ((bf16*)Cout)[(((size_t)(b * NHEAD + h)) * SEQ + s) * HDK + d] =
                __float2bfloat16(v);
        } else {
            if (flag) ((bf16*)Cout)[(size_t)m * D_MODEL + n] = __float2bfloat16(v);
            else      ((float*)Cout)[(size_t)m * D_MODEL + n] = v;
        }
    }
}

// ---------------------------------------------------------------------------
// Scalar attention, one thread per (b,h,q) row. Two passes over kv:
// pass 1 finds the row max; pass 2 accumulates exp-weighted V. fp32 accum.
// q,k,v in (B,H,S,dk) bf16; writes concat (B,S,D) bf16.
// grid (SEQ/64, B*NHEAD), block 64.
// ---------------------------------------------------------------------------
__global__ void attn_scalar(const bf16* __restrict__ q,
                            const bf16* __restrict__ k,
                            const bf16* __restrict__ v,
                            bf16* __restrict__ c) {
    const int bh = blockIdx.y;
    const int qi = blockIdx.x * 64 + threadIdx.x;

    const bf16* qr = q + ((size_t)bh * SEQ + qi) * HDK;
    const bf16* kb = k + (size_t)bh * SEQ * HDK;
    const bf16* vb = v + (size_t)bh * SEQ * HDK;

    float qv[HDK];
    #pragma unroll
    for (int d = 0; d < HDK; ++d) qv[d] = __bfloat162float(qr[d]);

    float mmax = -3.0e38f;
    for (int j = 0; j < SEQ; ++j) {
        const bf16* kr = kb + (size_t)j * HDK;
        float s = 0.f;
        #pragma unroll
        for (int d = 0; d < HDK; ++d) s += qv[d] * __bfloat162float(kr[d]);
        mmax = fmaxf(mmax, s * 0.125f);
    }

    float num[HDK];
    #pragma unroll
    for (int d = 0; d < HDK; ++d) num[d] = 0.f;
    float den = 0.f;
    for (int j = 0; j < SEQ; ++j) {
        const bf16* kr = kb + (size_t)j * HDK;
        float s = 0.f;
        #pragma unroll
        for (int d = 0; d < HDK; ++d) s += qv[d] * __bfloat162float(kr[d]);
        const float p = expf(s * 0.125f - mmax);
        den += p;
        const bf16* vr = vb + (size_t)j * HDK;
        #pragma unroll
        for (int d = 0; d < HDK; ++d) num[d] += p * __bfloat162float(vr[d]);
    }

    const int b = bh >> 4, h = bh & (NHEAD - 1);
    const float inv = 1.f / den;
    #pragma unroll
    for (int d = 0; d < HDK; ++d)
        c[((size_t)(b * SEQ + qi)) * D_MODEL + h * HDK + d] =
            __float2bfloat16(num[d] * inv);
}

// ---------------------------------------------------------------------------
extern "C" void kernel_launch(void* const* d_in, const int* in_sizes, int n_in,
                              void* d_out, int out_size, void* d_ws, size_t ws_size,
                              hipStream_t stream) {
    const void* X  = d_in[0];
    const void* Y  = d_in[1];
    const void* qW = d_in[2];
    const void* qB = d_in[3];
    const void* kW = d_in[4];
    const void* kB = d_in[5];
    const void* vW = d_in[6];
    const void* vB = d_in[7];
    const void* oW = d_in[8];
    const void* oB = d_in[9];

    bf16* ws = (bf16*)d_ws;
    const size_t QSZ = (size_t)BATCH * SEQ * D_MODEL;   // 4M elems
    bf16* qbuf = ws;                 // (B,H,S,dk)
    bf16* kbuf = qbuf + QSZ;
    bf16* vbuf = kbuf + QSZ;
    bf16* cbuf = vbuf + QSZ;         // concat (B,S,D)
    int*  flag = (int*)(cbuf + QSZ); // at byte offset 32MB

    detect_dtype<<<1, 256, 0, stream>>>((const unsigned short*)X, flag);

    const int M = BATCH * SEQ;       // 4096
    proj_scalar<true, 0><<<M, 256, 0, stream>>>(Y, qW, qB, qbuf, flag);
    proj_scalar<true, 0><<<M, 256, 0, stream>>>(X, kW, kB, kbuf, flag);
    proj_scalar<true, 0><<<M, 256, 0, stream>>>(X, vW, vB, vbuf, flag);

    attn_scalar<<<dim3(SEQ / 64, BATCH * NHEAD), 64, 0, stream>>>(qbuf, kbuf,
                                                                  vbuf, cbuf);

    proj_scalar<false, 1><<<M, 256, 0, stream>>>(cbuf, oW, oB, d_out, flag);
}